// Round 8
// baseline (45.034 us; speedup 1.0000x reference)
//
#include <hip/hip_runtime.h>

// 4-level MoE routing loss, B=8, H=1024, ROUTE=64, 16x16 patches/level.
// d_in: out0, gt0, out1, gt1, out2, gt2, out3, gt3   (all fp32)
// d_out (fp32 flat): [0] loss | [1..8388609) label_patch (8,1024,1024)
//   | [+2048) moe_label as float | [+8192) score (8,4,16,16)
// ws: [0..8) packed u64: bits 0..51 fixed-point (2^48) loss sum, bits 52+
//     block-arrival counter. Zeroed per call by an 8-byte memsetAsync.
//
// R8 = R7 phase 1 (batch-issued loads) +
//  (a) loss folded back in via packed RETURNING atomic (R4 mechanism, now
//      unconfounded): one u64 atomicAdd per block; the add whose returned
//      counter == NPATCH-1 holds the complete fixed-point sum -> that
//      thread writes loss. Integer add = associative = deterministic.
//      No fences (kernel-end writeback covers host visibility).
//  (b) phase 2 rows written as 16 unaligned (4B-aligned) dwordx4 — CDNA
//      global multi-dword ops need only dword alignment; removes the
//      3/60/1 row split and its divergent tail.

#define NPATCH 2048
#define LOSS_SCALE 281474976710656.0   // 2^48; sum < 2^52 guaranteed
#define CNT_ONE (1ULL << 52)

__global__ __launch_bounds__(256) void fused_kernel(
    const float* __restrict__ out0, const float* __restrict__ gt0,
    const float* __restrict__ out1, const float* __restrict__ gt1,
    const float* __restrict__ out2, const float* __restrict__ gt2,
    const float* __restrict__ out3, const float* __restrict__ gt3,
    float* __restrict__ scoreOut,   // (B,4,16,16)
    float* __restrict__ moeF,       // moe_label as float
    float* __restrict__ lab,        // label_patch base (d_out+1)
    float* __restrict__ lossOut,    // d_out[0]
    unsigned long long* __restrict__ lossAcc)
{
    const int p = blockIdx.x;          // b*256 + l
    const int b = p >> 8;
    const int l = p & 255;
    const int py = l >> 4, px = l & 15;
    const int t = threadIdx.x;

    // ---------- phase 1: batch-issue all loads ----------
    const size_t base0 = (size_t)b * 1048576;
    const int rowB0 = py << 6, colB0 = px << 6;
    float4 o00, o01, o02, o03, q00, q01, q02, q03;
    {
        int i0 = t,        r0 = i0 >> 4, c0 = (i0 & 15) << 2;
        int i1 = t + 256,  r1 = i1 >> 4, c1 = (i1 & 15) << 2;
        int i2 = t + 512,  r2 = i2 >> 4, c2 = (i2 & 15) << 2;
        int i3 = t + 768,  r3 = i3 >> 4, c3 = (i3 & 15) << 2;
        size_t f0 = base0 + (size_t)(rowB0 + r0) * 1024 + (colB0 + c0);
        size_t f1 = base0 + (size_t)(rowB0 + r1) * 1024 + (colB0 + c1);
        size_t f2 = base0 + (size_t)(rowB0 + r2) * 1024 + (colB0 + c2);
        size_t f3 = base0 + (size_t)(rowB0 + r3) * 1024 + (colB0 + c3);
        o00 = *(const float4*)(out0 + f0);  q00 = *(const float4*)(gt0 + f0);
        o01 = *(const float4*)(out0 + f1);  q01 = *(const float4*)(gt0 + f1);
        o02 = *(const float4*)(out0 + f2);  q02 = *(const float4*)(gt0 + f2);
        o03 = *(const float4*)(out0 + f3);  q03 = *(const float4*)(gt0 + f3);
    }
    float4 o1v, q1v;
    {
        int r = t >> 3, c = (t & 7) << 2;
        size_t off = (size_t)b * 262144 + (size_t)((py << 5) + r) * 512 + ((px << 5) + c);
        o1v = *(const float4*)(out1 + off);  q1v = *(const float4*)(gt1 + off);
    }
    float4 o2v, q2v;
    {
        int tt = t & 63;
        int r = tt >> 2, c = (tt & 3) << 2;
        size_t off = (size_t)b * 65536 + (size_t)((py << 4) + r) * 256 + ((px << 4) + c);
        o2v = *(const float4*)(out2 + off);  q2v = *(const float4*)(gt2 + off);
    }
    float4 o3v, q3v;
    {
        int tt = t & 15;
        int r = tt >> 1, c = (tt & 1) << 2;
        size_t off = (size_t)b * 16384 + (size_t)((py << 3) + r) * 128 + ((px << 3) + c);
        o3v = *(const float4*)(out3 + off);  q3v = *(const float4*)(gt3 + off);
    }

    // ---------- accumulate ----------
    float err[4], gts[4];
    {
        float e = 0.f, g = 0.f;
        #define ACC(o, q) { \
            float dx = o.x - q.x, dy = o.y - q.y, dz = o.z - q.z, dw = o.w - q.w; \
            e += dx * dx + dy * dy + dz * dz + dw * dw; \
            g += q.x + q.y + q.z + q.w; }
        ACC(o00, q00) ACC(o01, q01) ACC(o02, q02) ACC(o03, q03)
        err[0] = e; gts[0] = g;
        e = 0.f; g = 0.f; ACC(o1v, q1v) err[1] = e; gts[1] = g;
        e = 0.f; g = 0.f; ACC(o2v, q2v)
        bool w0 = (t < 64);
        err[2] = w0 ? e : 0.f; gts[2] = w0 ? g : 0.f;
        e = 0.f; g = 0.f; ACC(o3v, q3v)
        bool l16 = (t < 16);
        err[3] = l16 ? e : 0.f; gts[3] = l16 ? g : 0.f;
        #undef ACC
    }

    for (int s = 32; s; s >>= 1) {
        #pragma unroll
        for (int i = 0; i < 4; ++i) {
            err[i] += __shfl_down(err[i], s, 64);
            gts[i] += __shfl_down(gts[i], s, 64);
        }
    }
    __shared__ float se[4][4], sg[4][4];
    __shared__ int sm;
    const int wave = t >> 6, lane = t & 63;
    if (lane == 0) {
        #pragma unroll
        for (int i = 0; i < 4; ++i) { se[i][wave] = err[i]; sg[i][wave] = gts[i]; }
    }
    __syncthreads();

    float E[4], S[4];
    int mloc = 0;
    if (t == 0) {
        #pragma unroll
        for (int i = 0; i < 4; ++i) {
            E[i] = se[i][0] + se[i][1] + se[i][2] + se[i][3];
            float G = sg[i][0] + sg[i][1] + sg[i][2] + sg[i][3];
            float kk = (float)((64 >> i) * (64 >> i));
            S[i] = E[i] / kk + E[i] / (G + 1e-10f);
        }
        float best = S[0];
        #pragma unroll
        for (int i = 1; i < 4; ++i)
            if (S[i] < best) { best = S[i]; mloc = i; }   // strict <, first-min
        sm = mloc;
    }
    __syncthreads();
    const int m = sm;

    // t0's global writes issue here, overlapping everyone's phase 2
    if (t == 0) {
        #pragma unroll
        for (int i = 0; i < 4; ++i)
            scoreOut[b * 1024 + i * 256 + l] = S[i];
        moeF[p] = (float)mloc;
        double tt = (double)E[0] / 8388608.0;
        if (mloc >= 1) tt += (double)E[1] / 2097152.0;
        if (mloc >= 2) tt += (double)E[2] / 524288.0;
        if (mloc >= 3) tt += (double)E[3] / 131072.0;
        unsigned long long fx =
            (unsigned long long)llrint(tt * LOSS_SCALE) + CNT_ONE;
        unsigned long long old = atomicAdd(lossAcc, fx);
        if ((old >> 52) == NPATCH - 1) {            // I'm the last arrival
            unsigned long long total = old + fx;
            lossOut[0] = (float)((double)(total & (CNT_ONE - 1)) / LOSS_SCALE);
        }
    }

    // ---------- phase 2: 64x64 label tile, 16 dwordx4 per row ----------
    // Row y starts at lab index R0 (R0 % 4 == 0, but lab = d_out+1 so byte
    // addr ≡ 4 mod 16). CDNA global dwordx4 needs only dword alignment.
    const size_t labBase = (size_t)b * 1048576 + (size_t)(py << 6) * 1024 + (px << 6);

    if (m == 0) {
        for (int idx = t; idx < 1024; idx += 256) {
            int y = idx >> 4, j = idx & 15;
            size_t R0 = labBase + (size_t)y * 1024;
            float4 v = *(const float4*)(gt0 + R0 + 4 * j);   // aligned load
            *(float4*)(lab + R0 + 4 * j) = v;                // 4B-aligned store
        }
    } else {
        const int k = 64 >> m, pad = (64 - k) >> 1, W = 1024 >> m;
        const float* gt = (m == 1) ? gt1 : (m == 2) ? gt2 : gt3;
        const size_t gbase = (size_t)b * W * W + (size_t)(py * k) * W + px * k;
        for (int idx = t; idx < 1024; idx += 256) {
            int y = idx >> 4, j = idx & 15;
            size_t R0 = labBase + (size_t)y * 1024;
            int iy = y - pad;
            bool rowIn = (unsigned)iy < (unsigned)k;
            const float* grow = gt + gbase + (size_t)iy * W;
            float4 v;
            #pragma unroll
            for (int u = 0; u < 4; ++u) {
                int ix = 4 * j + u - pad;
                float vv = 0.2f;
                if (rowIn && (unsigned)ix < (unsigned)k) vv = grow[ix];
                ((float*)&v)[u] = vv;
            }
            *(float4*)(lab + R0 + 4 * j) = v;
        }
    }
}

extern "C" void kernel_launch(void* const* d_in, const int* in_sizes, int n_in,
                              void* d_out, int out_size, void* d_ws, size_t ws_size,
                              hipStream_t stream) {
    const float* out0 = (const float*)d_in[0];
    const float* gt0  = (const float*)d_in[1];
    const float* out1 = (const float*)d_in[2];
    const float* gt1  = (const float*)d_in[3];
    const float* out2 = (const float*)d_in[4];
    const float* gt2  = (const float*)d_in[5];
    const float* out3 = (const float*)d_in[6];
    const float* gt3  = (const float*)d_in[7];

    float* o = (float*)d_out;
    float* lossOut  = o;
    float* labOut   = o + 1;
    float* moeFOut  = o + 8388609;
    float* scoreOut = o + 8390657;

    unsigned long long* lossAcc = (unsigned long long*)d_ws;

    hipMemsetAsync(d_ws, 0, 8, stream);   // zero packed accumulator (8 B)

    fused_kernel<<<NPATCH, 256, 0, stream>>>(
        out0, gt0, out1, gt1, out2, gt2, out3, gt3,
        scoreOut, moeFOut, labOut, lossOut, lossAcc);
}

// Round 9
// 30.112 us; speedup vs baseline: 1.4956x; 1.4956x over previous
//
#include <hip/hip_runtime.h>

// 4-level MoE routing loss, B=8, H=1024, ROUTE=64, 16x16 patches/level.
// d_in: out0, gt0, out1, gt1, out2, gt2, out3, gt3   (all fp32)
// d_out (fp32 flat): [0] loss | [1..8388609) label_patch (8,1024,1024)
//   | [+2048) moe_label as float | [+8192) score (8,4,16,16)
// ws: double lossTerm[2048] @0 (16KB).
//
// R9 = exact R6 (best: 30.8us) + XCD row-swizzle:
//   launch index q -> px = q>>7, row = q&127 (= b*16+py). Since 128%8==0,
//   q%8 == row%8: all 16 horizontally-adjacent tiles of one tile-row run
//   on ONE XCD, so the 4B-shifted tile-row seam cachelines merge in that
//   XCD's L2 instead of causing partial-line RMW writebacks on two XCDs.
//   (R6 FETCH=50.6MB vs ~33MB true input misses -> ~17MB suspected RMW.)
// Loss: per-block lossTerm -> 1-block deterministic reduce kernel.
// NO atomics (R4/R8: returning hot-line atomic costs ~14us — falsified 2x).

#define NPATCH 2048

__global__ __launch_bounds__(256) void fused_kernel(
    const float* __restrict__ out0, const float* __restrict__ gt0,
    const float* __restrict__ out1, const float* __restrict__ gt1,
    const float* __restrict__ out2, const float* __restrict__ gt2,
    const float* __restrict__ out3, const float* __restrict__ gt3,
    float* __restrict__ scoreOut,   // (B,4,16,16)
    float* __restrict__ moeF,       // moe_label as float
    float* __restrict__ lab,        // label_patch base (d_out+1)
    double* __restrict__ lossTerm)  // ws [2048]
{
    // XCD row-swizzle: all px of one (b,py) tile-row share an XCD.
    const int q = blockIdx.x;
    const int px = q >> 7;             // 0..15
    const int row = q & 127;           // b*16 + py
    const int b = row >> 4;
    const int py = row & 15;
    const int l = (py << 4) | px;
    const int p = (b << 8) | l;        // logical patch id for moe/lossTerm

    const float* PO[4] = {out0, out1, out2, out3};
    const float* PG[4] = {gt0, gt1, gt2, gt3};

    float err[4], gts[4];

    #pragma unroll
    for (int lev = 0; lev < 4; ++lev) {
        const int k  = 64 >> lev;          // compile-time per unrolled iter
        const int W  = 1024 >> lev;
        const int kv = k >> 2;
        const int nvec = k * kv;
        const int rowBase = py * k, colBase = px * k;
        const size_t base = (size_t)b * W * W;
        const float* po = PO[lev];
        const float* pg = PG[lev];

        float e = 0.f, g = 0.f;
        for (int idx = threadIdx.x; idx < nvec; idx += 256) {
            int r = idx / kv;
            int c = (idx % kv) * 4;
            size_t off = base + (size_t)(rowBase + r) * W + (colBase + c);
            float4 o = *(const float4*)(po + off);
            float4 qv = *(const float4*)(pg + off);
            float dx = o.x - qv.x, dy = o.y - qv.y, dz = o.z - qv.z, dw = o.w - qv.w;
            e += dx * dx + dy * dy + dz * dz + dw * dw;
            g += qv.x + qv.y + qv.z + qv.w;
        }
        err[lev] = e; gts[lev] = g;
    }

    for (int s = 32; s; s >>= 1) {
        #pragma unroll
        for (int i = 0; i < 4; ++i) {
            err[i] += __shfl_down(err[i], s, 64);
            gts[i] += __shfl_down(gts[i], s, 64);
        }
    }
    __shared__ float se[4][4], sg[4][4];
    __shared__ int smv;
    const int wave = threadIdx.x >> 6, lane = threadIdx.x & 63;
    if (lane == 0) {
        #pragma unroll
        for (int i = 0; i < 4; ++i) { se[i][wave] = err[i]; sg[i][wave] = gts[i]; }
    }
    __syncthreads();
    if (threadIdx.x == 0) {
        float E[4], S[4];
        #pragma unroll
        for (int i = 0; i < 4; ++i) {
            E[i] = se[i][0] + se[i][1] + se[i][2] + se[i][3];
            float G = sg[i][0] + sg[i][1] + sg[i][2] + sg[i][3];
            float kk = (float)((64 >> i) * (64 >> i));
            S[i] = E[i] / kk + E[i] / (G + 1e-10f);
            scoreOut[b * 1024 + i * 256 + l] = S[i];
        }
        int m = 0; float best = S[0];
        #pragma unroll
        for (int i = 1; i < 4; ++i)
            if (S[i] < best) { best = S[i]; m = i; }   // strict <, first-min
        moeF[p] = (float)m;
        smv = m;
        double t = (double)E[0] / 8388608.0;
        if (m >= 1) t += (double)E[1] / 2097152.0;
        if (m >= 2) t += (double)E[2] / 524288.0;
        if (m >= 3) t += (double)E[3] / 131072.0;
        lossTerm[p] = t;
    }
    __syncthreads();
    const int m = smv;

    // ---- phase 2: write own 64x64 label tile, vectorized stores ----
    // lab row start R0 = labBase + y*1024 (R0 % 4 == 0); d_out = lab+1 so
    // aligned float4 slots are lab[3+4j .. 6+4j], j=0..14; remainders are
    // lab[R0+0..2] and lab[R0+63].
    const size_t labBase = (size_t)b * 1048576 + (size_t)(py << 6) * 1024 + (px << 6);

    if (m == 0) {
        for (int idx = threadIdx.x; idx < 1024; idx += 256) {
            int y = idx >> 4, j = idx & 15;
            size_t R0 = labBase + (size_t)y * 1024;
            if (j < 15) {
                int x = 3 + 4 * j;
                float4 v;
                v.x = gt0[R0 + x];
                v.y = gt0[R0 + x + 1];
                v.z = gt0[R0 + x + 2];
                v.w = gt0[R0 + x + 3];
                *(float4*)(lab + R0 + x) = v;
            } else {
                lab[R0]      = gt0[R0];
                lab[R0 + 1]  = gt0[R0 + 1];
                lab[R0 + 2]  = gt0[R0 + 2];
                lab[R0 + 63] = gt0[R0 + 63];
            }
        }
    } else {
        const int k = 64 >> m, pad = (64 - k) >> 1, W = 1024 >> m;
        const float* gt = (m == 1) ? gt1 : (m == 2) ? gt2 : gt3;
        const size_t gbase = (size_t)b * W * W + (size_t)(py * k) * W + px * k;
        for (int idx = threadIdx.x; idx < 1024; idx += 256) {
            int y = idx >> 4, j = idx & 15;
            size_t R0 = labBase + (size_t)y * 1024;
            int iy = y - pad;
            bool rowIn = (unsigned)iy < (unsigned)k;
            const float* grow = gt + gbase + (size_t)iy * W;
            if (j < 15) {
                int x = 3 + 4 * j;
                float4 v;
                #pragma unroll
                for (int u = 0; u < 4; ++u) {
                    int ix = x + u - pad;
                    float vv = 0.2f;
                    if (rowIn && (unsigned)ix < (unsigned)k) vv = grow[ix];
                    ((float*)&v)[u] = vv;
                }
                *(float4*)(lab + R0 + x) = v;
            } else {
                #pragma unroll
                for (int u = 0; u < 3; ++u) {
                    int ix = u - pad;
                    float vv = 0.2f;
                    if (rowIn && (unsigned)ix < (unsigned)k) vv = grow[ix];
                    lab[R0 + u] = vv;
                }
                int ix = 63 - pad;
                float vv = 0.2f;
                if (rowIn && (unsigned)ix < (unsigned)k) vv = grow[ix];
                lab[R0 + 63] = vv;
            }
        }
    }
}

__global__ __launch_bounds__(256) void loss_kernel(
    const double* __restrict__ lossTerm, float* __restrict__ lossOut)
{
    double t = 0.0;
    for (int i = threadIdx.x; i < NPATCH; i += 256) t += lossTerm[i];
    for (int s = 32; s; s >>= 1) t += __shfl_down(t, s, 64);
    __shared__ double sd[4];
    const int wave = threadIdx.x >> 6, lane = threadIdx.x & 63;
    if (lane == 0) sd[wave] = t;
    __syncthreads();
    if (threadIdx.x == 0)
        lossOut[0] = (float)(sd[0] + sd[1] + sd[2] + sd[3]);
}

extern "C" void kernel_launch(void* const* d_in, const int* in_sizes, int n_in,
                              void* d_out, int out_size, void* d_ws, size_t ws_size,
                              hipStream_t stream) {
    const float* out0 = (const float*)d_in[0];
    const float* gt0  = (const float*)d_in[1];
    const float* out1 = (const float*)d_in[2];
    const float* gt1  = (const float*)d_in[3];
    const float* out2 = (const float*)d_in[4];
    const float* gt2  = (const float*)d_in[5];
    const float* out3 = (const float*)d_in[6];
    const float* gt3  = (const float*)d_in[7];

    float* o = (float*)d_out;
    float* lossOut  = o;
    float* labOut   = o + 1;
    float* moeFOut  = o + 8388609;
    float* scoreOut = o + 8390657;

    double* lossTerm = (double*)d_ws;

    fused_kernel<<<NPATCH, 256, 0, stream>>>(
        out0, gt0, out1, gt1, out2, gt2, out3, gt3,
        scoreOut, moeFOut, labOut, lossTerm);
    loss_kernel<<<1, 256, 0, stream>>>(lossTerm, lossOut);
}